// Round 1
// baseline (1439.773 us; speedup 1.0000x reference)
//
#include <hip/hip_runtime.h>
#include <hip/hip_bf16.h>

#define BSZ   2
#define SEQ   2048
#define DIN   1024
#define EMB   1024
#define NH    16
#define HDIM  64
#define QKV3  (3 * EMB)   // 3072

// ---------------------------------------------------------------------------
// C[M][N] = A[M][K] @ W[N][K]^T + bias[N]     (both A and W are K-major: "NT")
// 64x64 tile, BK=16, 256 threads, 4x4 register blocking.
// LDS layout [kk][row] padded to 65 -> conflict-free-ish scalar reads.
// ---------------------------------------------------------------------------
__global__ __launch_bounds__(256) void gemm_nt(
    const float* __restrict__ A, const float* __restrict__ W,
    const float* __restrict__ bias, float* __restrict__ C,
    int M, int N, int K)
{
    __shared__ float As[16][65];
    __shared__ float Ws[16][65];

    const int tid = threadIdx.x;
    const int tx  = tid & 15;   // n direction
    const int ty  = tid >> 4;   // m direction
    const int m0  = blockIdx.y * 64;
    const int n0  = blockIdx.x * 64;

    float acc[4][4] = {};

    for (int k0 = 0; k0 < K; k0 += 16) {
        #pragma unroll
        for (int i = 0; i < 4; ++i) {
            int li = tid + i * 256;     // 0..1023 covers 64 rows x 16 k
            int r  = li >> 4;
            int kk = li & 15;
            As[kk][r] = A[(m0 + r) * K + k0 + kk];
            Ws[kk][r] = W[(n0 + r) * K + k0 + kk];
        }
        __syncthreads();

        #pragma unroll
        for (int kk = 0; kk < 16; ++kk) {
            float av[4], wv[4];
            #pragma unroll
            for (int i = 0; i < 4; ++i) av[i] = As[kk][ty * 4 + i];
            #pragma unroll
            for (int j = 0; j < 4; ++j) wv[j] = Ws[kk][tx * 4 + j];
            #pragma unroll
            for (int i = 0; i < 4; ++i)
                #pragma unroll
                for (int j = 0; j < 4; ++j)
                    acc[i][j] += av[i] * wv[j];
        }
        __syncthreads();
    }

    #pragma unroll
    for (int i = 0; i < 4; ++i) {
        int m = m0 + ty * 4 + i;
        #pragma unroll
        for (int j = 0; j < 4; ++j) {
            int n = n0 + tx * 4 + j;
            C[m * N + n] = acc[i][j] + bias[n];
        }
    }
}

// ---------------------------------------------------------------------------
// Flash-style attention, fp32.
// grid: (SEQ/64, NH, BSZ), block: 256 threads.
// Each block: 64 q-rows of one (b,h). K/V staged in LDS per 64-wide tile,
// online softmax (running m,l), accumulator rescale, write [B,S,H*HD].
// qkv layout: row (b*SEQ+s), per-head interleave: col = h*192 + {0,64,128} + d
// ---------------------------------------------------------------------------
__global__ __launch_bounds__(256) void attn_fwd(
    const float* __restrict__ qkv, float* __restrict__ attn_out)
{
    __shared__ float q_sh[64][65];
    __shared__ float kv_sh[64][65];
    __shared__ float sc[64][65];
    __shared__ float row_m[64], row_l[64], row_a[64];

    const int tid = threadIdx.x;
    const int qt  = blockIdx.x;
    const int h   = blockIdx.y;
    const int b   = blockIdx.z;
    const int tr  = tid >> 4;   // 0..15: row group (4 rows each)
    const int tc  = tid & 15;   // 0..15: col group (4 cols each)

    const int row0  = b * SEQ + qt * 64;   // first q row (global row into qkv)
    const int col_q = h * 192;
    const int col_k = h * 192 + 64;
    const int col_v = h * 192 + 128;

    // Load Q tile, pre-scaled by 1/sqrt(HD)
    #pragma unroll
    for (int i = 0; i < 16; ++i) {
        int li = tid + i * 256;          // 0..4095
        int r = li >> 6, d = li & 63;
        q_sh[r][d] = qkv[(row0 + r) * QKV3 + col_q + d] * 0.125f;
    }
    if (tid < 64) { row_m[tid] = -1e30f; row_l[tid] = 0.0f; }

    float acc[4][4] = {};
    __syncthreads();

    for (int kt = 0; kt < SEQ / 64; ++kt) {
        const int krow0 = b * SEQ + kt * 64;

        // ---- stage K tile ----
        #pragma unroll
        for (int i = 0; i < 16; ++i) {
            int li = tid + i * 256;
            int r = li >> 6, d = li & 63;
            kv_sh[r][d] = qkv[(krow0 + r) * QKV3 + col_k + d];
        }
        __syncthreads();

        // ---- scores: 4x4 per thread ----
        float s[4][4] = {};
        for (int d = 0; d < 64; ++d) {
            float qv[4], kv[4];
            #pragma unroll
            for (int i = 0; i < 4; ++i) qv[i] = q_sh[tr * 4 + i][d];
            #pragma unroll
            for (int j = 0; j < 4; ++j) kv[j] = kv_sh[tc * 4 + j][d];
            #pragma unroll
            for (int i = 0; i < 4; ++i)
                #pragma unroll
                for (int j = 0; j < 4; ++j)
                    s[i][j] += qv[i] * kv[j];
        }
        #pragma unroll
        for (int i = 0; i < 4; ++i)
            #pragma unroll
            for (int j = 0; j < 4; ++j)
                sc[tr * 4 + i][tc * 4 + j] = s[i][j];
        __syncthreads();

        // ---- online softmax update (one thread per row) ----
        if (tid < 64) {
            int r = tid;
            float mold = row_m[r];
            float mx = mold;
            for (int k = 0; k < 64; ++k) mx = fmaxf(mx, sc[r][k]);
            float alpha = __expf(mold - mx);
            float sum = 0.0f;
            for (int k = 0; k < 64; ++k) {
                float p = __expf(sc[r][k] - mx);
                sc[r][k] = p;
                sum += p;
            }
            row_l[r] = row_l[r] * alpha + sum;
            row_m[r] = mx;
            row_a[r] = alpha;
        }
        __syncthreads();

        // ---- stage V tile (kv_sh reuse; score phase done with K) ----
        #pragma unroll
        for (int i = 0; i < 16; ++i) {
            int li = tid + i * 256;
            int r = li >> 6, d = li & 63;
            kv_sh[r][d] = qkv[(krow0 + r) * QKV3 + col_v + d];
        }
        __syncthreads();

        // ---- rescale accumulator + PV ----
        float af[4];
        #pragma unroll
        for (int i = 0; i < 4; ++i) af[i] = row_a[tr * 4 + i];
        #pragma unroll
        for (int i = 0; i < 4; ++i)
            #pragma unroll
            for (int j = 0; j < 4; ++j)
                acc[i][j] *= af[i];

        for (int k = 0; k < 64; ++k) {
            float vv[4];
            #pragma unroll
            for (int j = 0; j < 4; ++j) vv[j] = kv_sh[k][tc * 4 + j];
            #pragma unroll
            for (int i = 0; i < 4; ++i) {
                float p = sc[tr * 4 + i][k];
                #pragma unroll
                for (int j = 0; j < 4; ++j)
                    acc[i][j] += p * vv[j];
            }
        }
        __syncthreads();   // before next tile overwrites kv_sh / sc
    }

    // ---- epilogue: divide by l, write [B,S,H*HD] ----
    #pragma unroll
    for (int i = 0; i < 4; ++i) {
        int r = tr * 4 + i;
        float inv = 1.0f / row_l[r];
        #pragma unroll
        for (int j = 0; j < 4; ++j)
            attn_out[(row0 + r) * EMB + h * HDIM + tc * 4 + j] = acc[i][j] * inv;
    }
}

// ---------------------------------------------------------------------------
extern "C" void kernel_launch(void* const* d_in, const int* in_sizes, int n_in,
                              void* d_out, int out_size, void* d_ws, size_t ws_size,
                              hipStream_t stream) {
    const float* x     = (const float*)d_in[0];  // [B,S,DIN]
    const float* W_qkv = (const float*)d_in[1];  // [3E, DIN]
    const float* b_qkv = (const float*)d_in[2];  // [3E]
    const float* W_out = (const float*)d_in[3];  // [E, E]
    const float* b_out = (const float*)d_in[4];  // [E]
    float* out = (float*)d_out;                  // [B,S,E]

    float* qkv     = (float*)d_ws;                         // [B*S, 3E] = 48 MB
    float* attnbuf = qkv + (size_t)BSZ * SEQ * QKV3;       // [B*S, E]  = 16 MB

    const int M = BSZ * SEQ;   // 4096

    // 1) QKV projection: [4096,1024] @ [3072,1024]^T
    gemm_nt<<<dim3(QKV3 / 64, M / 64), 256, 0, stream>>>(
        x, W_qkv, b_qkv, qkv, M, QKV3, DIN);

    // 2) attention
    attn_fwd<<<dim3(SEQ / 64, NH, BSZ), 256, 0, stream>>>(qkv, attnbuf);

    // 3) output projection: [4096,1024] @ [1024,1024]^T
    gemm_nt<<<dim3(EMB / 64, M / 64), 256, 0, stream>>>(
        attnbuf, W_out, b_out, out, M, EMB, DIN);
}

// Round 2
// 235.165 us; speedup vs baseline: 6.1224x; 6.1224x over previous
//
#include <hip/hip_runtime.h>
#include <hip/hip_bf16.h>

#define BSZ 2
#define SEQ 2048
#define DIN 1024
#define EMB 1024
#define NH  16
#define HD  64
#define QKV3 3072

typedef short bf16x8 __attribute__((ext_vector_type(8)));
typedef float f32x4  __attribute__((ext_vector_type(4)));

__device__ __forceinline__ unsigned short f2bf(float f) {
    union { float f; unsigned int u; } v; v.f = f;
    unsigned int r = v.u + 0x7fffu + ((v.u >> 16) & 1u);   // RNE
    return (unsigned short)(r >> 16);
}

// ---------------------------------------------------------------------------
// fp32 -> bf16 elementwise conversion (8 elems/thread)
// ---------------------------------------------------------------------------
__global__ __launch_bounds__(256) void f2bf_kernel(
    const float* __restrict__ in, unsigned short* __restrict__ out, int n)
{
    int i = (blockIdx.x * 256 + threadIdx.x) * 8;
    if (i >= n) return;
    float4 a = *(const float4*)(in + i);
    float4 b = *(const float4*)(in + i + 4);
    bf16x8 r;
    r[0] = (short)f2bf(a.x); r[1] = (short)f2bf(a.y);
    r[2] = (short)f2bf(a.z); r[3] = (short)f2bf(a.w);
    r[4] = (short)f2bf(b.x); r[5] = (short)f2bf(b.y);
    r[6] = (short)f2bf(b.z); r[7] = (short)f2bf(b.w);
    *(bf16x8*)(out + i) = r;
}

// ---------------------------------------------------------------------------
// bf16 MFMA GEMM: C[M][N] = A[M][K] @ W[N][K]^T + bias  (NT, both K-major)
// 128x128 tile, BK=32, 256 thr (4 waves 2x2), 16x16x32 MFMA, 4x4 frags/wave.
// LDS stride 40 shorts (80B) -> 16B-aligned b128, spread banks.
// ---------------------------------------------------------------------------
template <int OUT_BF16>
__global__ __launch_bounds__(256) void gemm_bf16_nt(
    const unsigned short* __restrict__ A, const unsigned short* __restrict__ W,
    const float* __restrict__ bias, void* __restrict__ Cout,
    int M, int N, int K)
{
    __shared__ short As[128 * 40];
    __shared__ short Bs[128 * 40];

    const int tid = threadIdx.x;
    const int m0 = blockIdx.y * 128, n0 = blockIdx.x * 128;
    const int w = tid >> 6, lane = tid & 63;
    const int lg = lane >> 4, l15 = lane & 15;
    const int wr = w >> 1, wc = w & 1;
    const int rr = tid >> 2, cc = tid & 3;

    f32x4 acc[4][4] = {};

    for (int k0 = 0; k0 < K; k0 += 32) {
        const unsigned short* Ap = A + (size_t)(m0 + rr) * K + k0 + cc * 8;
        const unsigned short* Wp = W + (size_t)(n0 + rr) * K + k0 + cc * 8;
        bf16x8 a0 = *(const bf16x8*)Ap;
        bf16x8 a1 = *(const bf16x8*)(Ap + (size_t)64 * K);
        bf16x8 b0 = *(const bf16x8*)Wp;
        bf16x8 b1 = *(const bf16x8*)(Wp + (size_t)64 * K);
        *(bf16x8*)&As[rr * 40 + cc * 8]        = a0;
        *(bf16x8*)&As[(rr + 64) * 40 + cc * 8] = a1;
        *(bf16x8*)&Bs[rr * 40 + cc * 8]        = b0;
        *(bf16x8*)&Bs[(rr + 64) * 40 + cc * 8] = b1;
        __syncthreads();

        bf16x8 af[4], bfr[4];
        #pragma unroll
        for (int mf = 0; mf < 4; ++mf)
            af[mf] = *(const bf16x8*)&As[(wr * 64 + mf * 16 + l15) * 40 + lg * 8];
        #pragma unroll
        for (int nf = 0; nf < 4; ++nf)
            bfr[nf] = *(const bf16x8*)&Bs[(wc * 64 + nf * 16 + l15) * 40 + lg * 8];
        #pragma unroll
        for (int mf = 0; mf < 4; ++mf)
            #pragma unroll
            for (int nf = 0; nf < 4; ++nf)
                acc[mf][nf] = __builtin_amdgcn_mfma_f32_16x16x32_bf16(
                    af[mf], bfr[nf], acc[mf][nf], 0, 0, 0);
        __syncthreads();
    }

    // epilogue: C/D layout col=lane&15, row=(lane>>4)*4+r  [verified m89]
    #pragma unroll
    for (int nf = 0; nf < 4; ++nf) {
        int col = n0 + wc * 64 + nf * 16 + l15;
        float bv = bias[col];
        #pragma unroll
        for (int mf = 0; mf < 4; ++mf) {
            #pragma unroll
            for (int r = 0; r < 4; ++r) {
                int row = m0 + wr * 64 + mf * 16 + lg * 4 + r;
                float v = acc[mf][nf][r] + bv;
                if (OUT_BF16)
                    ((unsigned short*)Cout)[(size_t)row * N + col] = f2bf(v);
                else
                    ((float*)Cout)[(size_t)row * N + col] = v;
            }
        }
    }
}

// ---------------------------------------------------------------------------
// MFMA flash attention. grid (SEQ/64, NH, BSZ), 256 thr (4 waves).
// Wave w owns q-rows [w*16, w*16+16). Q held in registers. Per 64-key tile:
// stage K (XOR-swizzled chunks) + V^T, QK^T MFMA -> Ss, online softmax
// (4 thr/row) -> Ps bf16 (XOR-swizzled), rescale O frags, PV MFMA.
// ---------------------------------------------------------------------------
__global__ __launch_bounds__(256) void attn_mfma(
    const unsigned short* __restrict__ qkvb,   // [B*S][3072] bf16
    unsigned short* __restrict__ attnb)        // [B*S][1024] bf16
{
    __shared__ short Ks[64 * 64];      // [key][chunk^(key&7) swizzled], 128B rows
    __shared__ short VT[64 * 72];      // [d][key], stride 72
    __shared__ float Ss[64 * 68];      // scores fp32, stride 68
    __shared__ short Ps[64 * 64];      // P bf16, swizzled like Ks
    __shared__ float row_m[64], row_l[64], row_al[64];

    const int tid = threadIdx.x;
    const int qt = blockIdx.x, h = blockIdx.y, b = blockIdx.z;
    const int w = tid >> 6, lane = tid & 63;
    const int lg = lane >> 4, l15 = lane & 15;

    const int row0 = b * SEQ + qt * 64;
    const int colq = h * 192, colk = colq + 64, colv = colq + 128;

    // Q fragments in registers (k = kc*32 + lg*8 + j, consistent A/B mapping)
    bf16x8 qa[2];
    {
        const unsigned short* qp =
            qkvb + (size_t)(row0 + w * 16 + l15) * QKV3 + colq + lg * 8;
        qa[0] = *(const bf16x8*)qp;
        qa[1] = *(const bf16x8*)(qp + 32);
    }
    if (tid < 64) { row_m[tid] = -INFINITY; row_l[tid] = 0.0f; }

    f32x4 o[4] = {};
    __syncthreads();

    for (int kt = 0; kt < SEQ / 64; ++kt) {
        const size_t krow0 = (size_t)(b * SEQ + kt * 64);

        // ---- stage K (swizzled) and V^T ----
        #pragma unroll
        for (int i = 0; i < 2; ++i) {
            int id = tid + i * 256;          // 0..511
            int key = id >> 3, c = id & 7;   // 64 keys x 8 chunks(16B)
            const unsigned short* kp = qkvb + (krow0 + key) * QKV3 + colk + c * 8;
            const unsigned short* vp = qkvb + (krow0 + key) * QKV3 + colv + c * 8;
            bf16x8 kv = *(const bf16x8*)kp;
            bf16x8 vv = *(const bf16x8*)vp;
            *(bf16x8*)&Ks[key * 64 + ((c ^ (key & 7)) << 3)] = kv;
            #pragma unroll
            for (int jj = 0; jj < 8; ++jj)
                VT[(c * 8 + jj) * 72 + key] = vv[jj];
        }
        __syncthreads();

        // ---- QK^T: wave's 16 q-rows x 64 keys ----
        f32x4 s[4] = {};
        #pragma unroll
        for (int kc = 0; kc < 2; ++kc) {
            #pragma unroll
            for (int nf = 0; nf < 4; ++nf) {
                int key = nf * 16 + l15;
                int ch = (kc * 4 + lg) ^ (key & 7);
                bf16x8 bfr = *(const bf16x8*)&Ks[key * 64 + (ch << 3)];
                s[nf] = __builtin_amdgcn_mfma_f32_16x16x32_bf16(qa[kc], bfr, s[nf], 0, 0, 0);
            }
        }
        #pragma unroll
        for (int nf = 0; nf < 4; ++nf)
            #pragma unroll
            for (int r = 0; r < 4; ++r)
                Ss[(w * 16 + lg * 4 + r) * 68 + nf * 16 + l15] = s[nf][r] * 0.125f;
        __syncthreads();

        // ---- online softmax: 4 threads per row ----
        {
            int r = tid >> 2, qq = tid & 3;
            const float* sp = &Ss[r * 68 + qq * 16];
            float pv[16];
            #pragma unroll
            for (int j4 = 0; j4 < 4; ++j4) {
                float4 t = *(const float4*)(sp + j4 * 4);
                pv[j4 * 4 + 0] = t.x; pv[j4 * 4 + 1] = t.y;
                pv[j4 * 4 + 2] = t.z; pv[j4 * 4 + 3] = t.w;
            }
            float mx = pv[0];
            #pragma unroll
            for (int j = 1; j < 16; ++j) mx = fmaxf(mx, pv[j]);
            mx = fmaxf(mx, __shfl_xor(mx, 1, 4));
            mx = fmaxf(mx, __shfl_xor(mx, 2, 4));
            float mold = row_m[r];
            float mnew = fmaxf(mold, mx);
            float al = __expf(mold - mnew);
            float sum = 0.0f;
            unsigned short pb[16];
            #pragma unroll
            for (int j = 0; j < 16; ++j) {
                float e = __expf(pv[j] - mnew);
                sum += e;
                pb[j] = f2bf(e);
            }
            sum += __shfl_xor(sum, 1, 4);
            sum += __shfl_xor(sum, 2, 4);
            if (qq == 0) {
                row_m[r] = mnew;
                row_l[r] = row_l[r] * al + sum;
                row_al[r] = al;
            }
            bf16x8 p0, p1;
            #pragma unroll
            for (int j = 0; j < 8; ++j) { p0[j] = (short)pb[j]; p1[j] = (short)pb[8 + j]; }
            *(bf16x8*)&Ps[r * 64 + ((((qq << 1) | 0) ^ (r & 7)) << 3)] = p0;
            *(bf16x8*)&Ps[r * 64 + ((((qq << 1) | 1) ^ (r & 7)) << 3)] = p1;
        }
        __syncthreads();

        // ---- rescale O, then PV MFMA ----
        float av[4];
        #pragma unroll
        for (int r = 0; r < 4; ++r) av[r] = row_al[w * 16 + lg * 4 + r];
        #pragma unroll
        for (int nf = 0; nf < 4; ++nf)
            #pragma unroll
            for (int r = 0; r < 4; ++r)
                o[nf][r] *= av[r];

        #pragma unroll
        for (int kc = 0; kc < 2; ++kc) {
            int prow = w * 16 + l15;
            int ch = (kc * 4 + lg) ^ (prow & 7);
            bf16x8 pa = *(const bf16x8*)&Ps[prow * 64 + (ch << 3)];
            #pragma unroll
            for (int nf = 0; nf < 4; ++nf) {
                bf16x8 vb = *(const bf16x8*)&VT[(nf * 16 + l15) * 72 + kc * 32 + lg * 8];
                o[nf] = __builtin_amdgcn_mfma_f32_16x16x32_bf16(pa, vb, o[nf], 0, 0, 0);
            }
        }
        __syncthreads();   // protect Ks/VT/Ss/Ps for next tile's staging
    }

    // ---- epilogue: O / l -> attnb [token][h*64 + d] bf16 ----
    #pragma unroll
    for (int nf = 0; nf < 4; ++nf) {
        #pragma unroll
        for (int r = 0; r < 4; ++r) {
            int qrow = w * 16 + lg * 4 + r;
            float inv = 1.0f / row_l[qrow];
            attnb[(size_t)(row0 + qrow) * EMB + h * HD + nf * 16 + l15] =
                f2bf(o[nf][r] * inv);
        }
    }
}

// ---------------------------------------------------------------------------
extern "C" void kernel_launch(void* const* d_in, const int* in_sizes, int n_in,
                              void* d_out, int out_size, void* d_ws, size_t ws_size,
                              hipStream_t stream) {
    const float* x     = (const float*)d_in[0];
    const float* W_qkv = (const float*)d_in[1];
    const float* b_qkv = (const float*)d_in[2];
    const float* W_out = (const float*)d_in[3];
    const float* b_out = (const float*)d_in[4];
    float* out = (float*)d_out;

    // workspace layout (bytes): xb 8M | wqkvb 6M | woutb 2M | qkvb 24M | attnb 8M
    char* ws = (char*)d_ws;
    unsigned short* xb     = (unsigned short*)(ws);
    unsigned short* wqkvb  = (unsigned short*)(ws + (8u << 20));
    unsigned short* woutb  = (unsigned short*)(ws + (14u << 20));
    unsigned short* qkvb   = (unsigned short*)(ws + (16u << 20));
    unsigned short* attnb  = (unsigned short*)(ws + (40u << 20));

    const int M = BSZ * SEQ;            // 4096
    const int nx = M * DIN;             // 4194304
    const int nwq = QKV3 * DIN;         // 3145728
    const int nwo = EMB * EMB;          // 1048576

    f2bf_kernel<<<nx  / (8 * 256), 256, 0, stream>>>(x,     xb,    nx);
    f2bf_kernel<<<nwq / (8 * 256), 256, 0, stream>>>(W_qkv, wqkvb, nwq);
    f2bf_kernel<<<nwo / (8 * 256), 256, 0, stream>>>(W_out, woutb, nwo);

    // QKV projection: [4096,1024] @ [3072,1024]^T -> bf16 qkv
    gemm_bf16_nt<1><<<dim3(QKV3 / 128, M / 128), 256, 0, stream>>>(
        xb, wqkvb, b_qkv, qkvb, M, QKV3, DIN);

    // attention
    attn_mfma<<<dim3(SEQ / 64, NH, BSZ), 256, 0, stream>>>(qkvb, attnb);

    // output projection: [4096,1024] @ [1024,1024]^T -> fp32 out
    gemm_bf16_nt<0><<<dim3(EMB / 128, M / 128), 256, 0, stream>>>(
        attnb, woutb, b_out, out, M, EMB, DIN);
}

// Round 3
// 171.481 us; speedup vs baseline: 8.3961x; 1.3714x over previous
//
#include <hip/hip_runtime.h>
#include <hip/hip_bf16.h>

#define BSZ 2
#define SEQ 2048
#define DIN 1024
#define EMB 1024
#define NH  16
#define HD  64
#define QKV3 3072

typedef short bf16x8 __attribute__((ext_vector_type(8)));
typedef float f32x4  __attribute__((ext_vector_type(4)));

__device__ __forceinline__ unsigned short f2bf(float f) {
    union { float f; unsigned int u; } v; v.f = f;
    unsigned int r = v.u + 0x7fffu + ((v.u >> 16) & 1u);   // RNE
    return (unsigned short)(r >> 16);
}

// ---------------------------------------------------------------------------
// fp32 -> bf16 elementwise conversion (8 elems/thread)
// ---------------------------------------------------------------------------
__global__ __launch_bounds__(256) void f2bf_kernel(
    const float* __restrict__ in, unsigned short* __restrict__ out, int n)
{
    int i = (blockIdx.x * 256 + threadIdx.x) * 8;
    if (i >= n) return;
    float4 a = *(const float4*)(in + i);
    float4 b = *(const float4*)(in + i + 4);
    bf16x8 r;
    r[0] = (short)f2bf(a.x); r[1] = (short)f2bf(a.y);
    r[2] = (short)f2bf(a.z); r[3] = (short)f2bf(a.w);
    r[4] = (short)f2bf(b.x); r[5] = (short)f2bf(b.y);
    r[6] = (short)f2bf(b.z); r[7] = (short)f2bf(b.w);
    *(bf16x8*)(out + i) = r;
}

// ---------------------------------------------------------------------------
// bf16 MFMA GEMM: C[M][N] = A[M][K] @ W[N][K]^T + bias  (NT, both K-major)
// 128x128 tile, BK=32, 256 thr (4 waves 2x2), 16x16x32 MFMA, 4x4 frags/wave.
// ---------------------------------------------------------------------------
template <int OUT_BF16>
__global__ __launch_bounds__(256) void gemm_bf16_nt(
    const unsigned short* __restrict__ A, const unsigned short* __restrict__ W,
    const float* __restrict__ bias, void* __restrict__ Cout,
    int M, int N, int K)
{
    __shared__ short As[128 * 40];
    __shared__ short Bs[128 * 40];

    const int tid = threadIdx.x;
    const int m0 = blockIdx.y * 128, n0 = blockIdx.x * 128;
    const int w = tid >> 6, lane = tid & 63;
    const int lg = lane >> 4, l15 = lane & 15;
    const int wr = w >> 1, wc = w & 1;
    const int rr = tid >> 2, cc = tid & 3;

    f32x4 acc[4][4] = {};

    for (int k0 = 0; k0 < K; k0 += 32) {
        const unsigned short* Ap = A + (size_t)(m0 + rr) * K + k0 + cc * 8;
        const unsigned short* Wp = W + (size_t)(n0 + rr) * K + k0 + cc * 8;
        bf16x8 a0 = *(const bf16x8*)Ap;
        bf16x8 a1 = *(const bf16x8*)(Ap + (size_t)64 * K);
        bf16x8 b0 = *(const bf16x8*)Wp;
        bf16x8 b1 = *(const bf16x8*)(Wp + (size_t)64 * K);
        *(bf16x8*)&As[rr * 40 + cc * 8]        = a0;
        *(bf16x8*)&As[(rr + 64) * 40 + cc * 8] = a1;
        *(bf16x8*)&Bs[rr * 40 + cc * 8]        = b0;
        *(bf16x8*)&Bs[(rr + 64) * 40 + cc * 8] = b1;
        __syncthreads();

        bf16x8 af[4], bfr[4];
        #pragma unroll
        for (int mf = 0; mf < 4; ++mf)
            af[mf] = *(const bf16x8*)&As[(wr * 64 + mf * 16 + l15) * 40 + lg * 8];
        #pragma unroll
        for (int nf = 0; nf < 4; ++nf)
            bfr[nf] = *(const bf16x8*)&Bs[(wc * 64 + nf * 16 + l15) * 40 + lg * 8];
        #pragma unroll
        for (int mf = 0; mf < 4; ++mf)
            #pragma unroll
            for (int nf = 0; nf < 4; ++nf)
                acc[mf][nf] = __builtin_amdgcn_mfma_f32_16x16x32_bf16(
                    af[mf], bfr[nf], acc[mf][nf], 0, 0, 0);
        __syncthreads();
    }

    #pragma unroll
    for (int nf = 0; nf < 4; ++nf) {
        int col = n0 + wc * 64 + nf * 16 + l15;
        float bv = bias[col];
        #pragma unroll
        for (int mf = 0; mf < 4; ++mf) {
            #pragma unroll
            for (int r = 0; r < 4; ++r) {
                int row = m0 + wr * 64 + mf * 16 + lg * 4 + r;
                float v = acc[mf][nf][r] + bv;
                if (OUT_BF16)
                    ((unsigned short*)Cout)[(size_t)row * N + col] = f2bf(v);
                else
                    ((float*)Cout)[(size_t)row * N + col] = v;
            }
        }
    }
}

// ---------------------------------------------------------------------------
// V pre-transpose: vtg[b][h][d][s] <- qkv V-part [b*S+s][h*192+128+d]
// grid (32 s-tiles, NH, BSZ) x 256. Gather-read u16 (L1-hot lines: each V-row
// is exactly one 128B line), coalesced b128 stores.
// ---------------------------------------------------------------------------
__global__ __launch_bounds__(256) void vtranspose(
    const unsigned short* __restrict__ qkvb, unsigned short* __restrict__ vtg)
{
    const int tid = threadIdx.x;
    const int st = blockIdx.x, h = blockIdx.y, bz = blockIdx.z;
    const int colv = h * 192 + 128;

    #pragma unroll
    for (int i = 0; i < 2; ++i) {
        int id = tid + i * 256;          // 0..511
        int d = id >> 3, sc = id & 7;    // 64 d x 8 s-chunks
        bf16x8 v;
        #pragma unroll
        for (int jj = 0; jj < 8; ++jj)
            v[jj] = (short)qkvb[(size_t)(bz * SEQ + st * 64 + sc * 8 + jj) * QKV3 + colv + d];
        *(bf16x8*)&vtg[((size_t)(bz * NH + h) * HD + d) * SEQ + st * 64 + sc * 8] = v;
    }
}

// ---------------------------------------------------------------------------
// MFMA flash attention, swapped-QK^T + in-register softmax.
// grid 1024 (XCD-swizzled -> (qt,h,b)), 256 thr (4 waves x 16 q-rows).
// Per 128-key tile: stage K[128][64] + VT[64][128] (XOR-swizzled), 2 barriers.
// S^T = mfma(K,Q): lane holds row q=lane&15, keys spread over 4 lanes ->
// shfl_xor(16/32) row reduce. P redistributed to PV A-frag via 8 shfl/32keys.
// ---------------------------------------------------------------------------
__global__ __launch_bounds__(256, 4) void attn_mfma(
    const unsigned short* __restrict__ qkvb,
    const unsigned short* __restrict__ vtg,
    unsigned short* __restrict__ attnb)
{
    __shared__ short Ks[128 * 64];     // [key][d], chunk^(key&7) swizzle
    __shared__ short VT[64 * 128];     // [d][key], chunk^(d&15) swizzle

    const int tid = threadIdx.x;
    const int fl = blockIdx.x;
    const int swz = ((fl & 7) << 7) | (fl >> 3);   // bijective XCD swizzle
    const int qt = swz & 31, h = (swz >> 5) & 15, b = swz >> 9;

    const int w = tid >> 6, lane = tid & 63;
    const int lg = lane >> 4, l15 = lane & 15;

    const int row0 = b * SEQ + qt * 64;
    const int colq = h * 192, colk = colq + 64;
    const float C = 0.18033688f;       // 0.125 * log2(e)

    // Q fragments (nominal layout row=q=l15, k=d=kc*32+lg*8+j)
    bf16x8 qa[2];
    {
        const unsigned short* qp =
            qkvb + (size_t)(row0 + w * 16 + l15) * QKV3 + colq + lg * 8;
        qa[0] = *(const bf16x8*)qp;
        qa[1] = *(const bf16x8*)(qp + 32);
    }
    const unsigned short* vbase = vtg + (size_t)(b * NH + h) * HD * SEQ;

    float m_run = -INFINITY, l_run = 0.0f;
    f32x4 o[4] = {};

    for (int kt = 0; kt < SEQ / 128; ++kt) {
        const size_t krow0 = (size_t)(b * SEQ + kt * 128);

        // ---- stage K tile [128][64] ----
        #pragma unroll
        for (int i = 0; i < 4; ++i) {
            int id = tid + i * 256;
            int key = id >> 3, c = id & 7;
            bf16x8 kv = *(const bf16x8*)(qkvb + (krow0 + key) * QKV3 + colk + c * 8);
            *(bf16x8*)&Ks[key * 64 + ((c ^ (key & 7)) << 3)] = kv;
        }
        // ---- stage V^T tile [64][128] ----
        #pragma unroll
        for (int i = 0; i < 4; ++i) {
            int id = tid + i * 256;
            int d = id >> 4, c = id & 15;
            bf16x8 vv = *(const bf16x8*)(vbase + (size_t)d * SEQ + kt * 128 + c * 8);
            *(bf16x8*)&VT[d * 128 + ((c ^ (d & 15)) << 3)] = vv;
        }
        __syncthreads();

        // ---- S^T = mfma(K, Q): lane holds S^T[key=kf*16+lg*4+r][q=l15] ----
        f32x4 s[8];
        #pragma unroll
        for (int kf = 0; kf < 8; ++kf) s[kf] = (f32x4){0.f, 0.f, 0.f, 0.f};
        #pragma unroll
        for (int kc = 0; kc < 2; ++kc) {
            #pragma unroll
            for (int kf = 0; kf < 8; ++kf) {
                int key = kf * 16 + l15;
                int ch = (kc * 4 + lg) ^ (key & 7);
                bf16x8 kfr = *(const bf16x8*)&Ks[key * 64 + (ch << 3)];
                s[kf] = __builtin_amdgcn_mfma_f32_16x16x32_bf16(kfr, qa[kc], s[kf], 0, 0, 0);
            }
        }

        // ---- in-register online softmax (row q=l15 across 4 lanes) ----
        float mx = -INFINITY;
        #pragma unroll
        for (int kf = 0; kf < 8; ++kf) {
            float m01 = fmaxf(s[kf][0], s[kf][1]);
            float m23 = fmaxf(s[kf][2], s[kf][3]);
            mx = fmaxf(mx, fmaxf(m01, m23));
        }
        mx = fmaxf(mx, __shfl_xor(mx, 16));
        mx = fmaxf(mx, __shfl_xor(mx, 32));
        float mnew = fmaxf(m_run, mx);
        float alpha = exp2f((m_run - mnew) * C);
        float mc = mnew * C;
        m_run = mnew;

        float sum = 0.0f;
        unsigned pk[8][2];
        #pragma unroll
        for (int kf = 0; kf < 8; ++kf) {
            float p0 = exp2f(s[kf][0] * C - mc);
            float p1 = exp2f(s[kf][1] * C - mc);
            float p2 = exp2f(s[kf][2] * C - mc);
            float p3 = exp2f(s[kf][3] * C - mc);
            sum += (p0 + p1) + (p2 + p3);
            pk[kf][0] = (unsigned)f2bf(p0) | ((unsigned)f2bf(p1) << 16);
            pk[kf][1] = (unsigned)f2bf(p2) | ((unsigned)f2bf(p3) << 16);
        }
        sum += __shfl_xor(sum, 16);
        sum += __shfl_xor(sum, 32);
        l_run = l_run * alpha + sum;

        // ---- rescale O (alpha for q=lg*4+r lives at lane lg*20+r) ----
        #pragma unroll
        for (int r = 0; r < 4; ++r) {
            float ar = __shfl(alpha, lg * 20 + r);
            #pragma unroll
            for (int nf = 0; nf < 4; ++nf) o[nf][r] *= ar;
        }

        // ---- PV: redistribute P to A-frag nominal (row=q=l15, k=key) ----
        const int srcA = ((lg & 1) << 5) | l15;
        const int srcB = srcA + 16;
        const bool hi = (lg >= 2);
        #pragma unroll
        for (int kc = 0; kc < 4; ++kc) {
            unsigned a0 = (unsigned)__shfl((int)pk[2 * kc][0], srcA);
            unsigned a1 = (unsigned)__shfl((int)pk[2 * kc][1], srcA);
            unsigned a2 = (unsigned)__shfl((int)pk[2 * kc][0], srcB);
            unsigned a3 = (unsigned)__shfl((int)pk[2 * kc][1], srcB);
            unsigned c0 = (unsigned)__shfl((int)pk[2 * kc + 1][0], srcA);
            unsigned c1 = (unsigned)__shfl((int)pk[2 * kc + 1][1], srcA);
            unsigned c2 = (unsigned)__shfl((int)pk[2 * kc + 1][0], srcB);
            unsigned c3 = (unsigned)__shfl((int)pk[2 * kc + 1][1], srcB);
            union { unsigned u[4]; bf16x8 v; } pa;
            pa.u[0] = hi ? c0 : a0;
            pa.u[1] = hi ? c1 : a1;
            pa.u[2] = hi ? c2 : a2;
            pa.u[3] = hi ? c3 : a3;
            #pragma unroll
            for (int nf = 0; nf < 4; ++nf) {
                int d = nf * 16 + l15;
                int ch = (kc * 4 + lg) ^ (d & 15);
                bf16x8 vb = *(const bf16x8*)&VT[d * 128 + (ch << 3)];
                o[nf] = __builtin_amdgcn_mfma_f32_16x16x32_bf16(pa.v, vb, o[nf], 0, 0, 0);
            }
        }
        __syncthreads();
    }

    // ---- epilogue: O[q=lg*4+r][d=nf*16+l15] / l ----
    #pragma unroll
    for (int r = 0; r < 4; ++r) {
        float lr = __shfl(l_run, lg * 20 + r);
        float inv = 1.0f / lr;
        int qrow = w * 16 + lg * 4 + r;
        #pragma unroll
        for (int nf = 0; nf < 4; ++nf)
            attnb[(size_t)(row0 + qrow) * EMB + h * HD + nf * 16 + l15] =
                f2bf(o[nf][r] * inv);
    }
}

// ---------------------------------------------------------------------------
extern "C" void kernel_launch(void* const* d_in, const int* in_sizes, int n_in,
                              void* d_out, int out_size, void* d_ws, size_t ws_size,
                              hipStream_t stream) {
    const float* x     = (const float*)d_in[0];
    const float* W_qkv = (const float*)d_in[1];
    const float* b_qkv = (const float*)d_in[2];
    const float* W_out = (const float*)d_in[3];
    const float* b_out = (const float*)d_in[4];
    float* out = (float*)d_out;

    // ws: xb 8M | wqkvb 6M | woutb 2M | qkvb 24M | attnb 8M | vtg 8M = 56 MB
    char* ws = (char*)d_ws;
    unsigned short* xb     = (unsigned short*)(ws);
    unsigned short* wqkvb  = (unsigned short*)(ws + (8u << 20));
    unsigned short* woutb  = (unsigned short*)(ws + (14u << 20));
    unsigned short* qkvb   = (unsigned short*)(ws + (16u << 20));
    unsigned short* attnb  = (unsigned short*)(ws + (40u << 20));
    unsigned short* vtg    = (unsigned short*)(ws + (48u << 20));

    const int M = BSZ * SEQ;            // 4096
    const int nx = M * DIN;
    const int nwq = QKV3 * DIN;
    const int nwo = EMB * EMB;

    f2bf_kernel<<<nx  / (8 * 256), 256, 0, stream>>>(x,     xb,    nx);
    f2bf_kernel<<<nwq / (8 * 256), 256, 0, stream>>>(W_qkv, wqkvb, nwq);
    f2bf_kernel<<<nwo / (8 * 256), 256, 0, stream>>>(W_out, woutb, nwo);

    gemm_bf16_nt<1><<<dim3(QKV3 / 128, M / 128), 256, 0, stream>>>(
        xb, wqkvb, b_qkv, qkvb, M, QKV3, DIN);

    vtranspose<<<dim3(SEQ / 64, NH, BSZ), 256, 0, stream>>>(qkvb, vtg);

    attn_mfma<<<1024, 256, 0, stream>>>(qkvb, vtg, attnb);

    gemm_bf16_nt<0><<<dim3(EMB / 128, M / 128), 256, 0, stream>>>(
        attnb, woutb, b_out, out, M, EMB, DIN);
}